// Round 1
// baseline (1392.170 us; speedup 1.0000x reference)
//
#include <hip/hip_runtime.h>

#define N_NODES_C 50000
#define N_EDGES_C 800000
#define D 128

// ---------------------------------------------------------------------------
// Kernel 1: alpha[i] = sigmoid(dot(x[i], alpha_w) + alpha_b)
// One 64-lane wave per node; each lane handles 2 of the 128 dims.
// Writes alpha to BOTH the output tail (d_out + N*D) and a workspace copy.
// ---------------------------------------------------------------------------
__global__ __launch_bounds__(256) void alpha_kernel(
    const float* __restrict__ x,
    const float* __restrict__ aw,
    const float* __restrict__ ab,
    float* __restrict__ alpha_out,
    float* __restrict__ alpha_ws,
    int n) {
  int wave = (int)((blockIdx.x * blockDim.x + threadIdx.x) >> 6);
  int lane = threadIdx.x & 63;
  if (wave >= n) return;
  const float* xr = x + (size_t)wave * D;
  float s = xr[lane] * aw[lane] + xr[lane + 64] * aw[lane + 64];
  #pragma unroll
  for (int off = 32; off > 0; off >>= 1)
    s += __shfl_down(s, off);
  if (lane == 0) {
    float a = 1.0f / (1.0f + __expf(-(s + ab[0])));
    alpha_out[wave] = a;
    alpha_ws[wave] = a;
  }
}

// ---------------------------------------------------------------------------
// Kernel 2: fused mixed SpMM scatter.
// z[r] += scale(r) * vals[e] * x[cols[e]]   with scale = alpha[r] (LP)
//                                             or 1-alpha[r]      (HP)
// 128 threads per edge (one per feature dim), 2 edges per 256-thread block.
// x reads coalesced; atomicAdds contiguous over 128 floats of one row.
// ---------------------------------------------------------------------------
__global__ __launch_bounds__(256) void edge_kernel(
    const int* __restrict__ rows,
    const int* __restrict__ cols,
    const float* __restrict__ vals,
    const float* __restrict__ x,
    const float* __restrict__ alpha,
    float* __restrict__ z,
    int n_edges, int is_hp) {
  int e = (int)(blockIdx.x * 2 + (threadIdx.x >> 7));
  int d = threadIdx.x & 127;
  if (e >= n_edges) return;
  int r = rows[e];
  int c = cols[e];
  float a = alpha[r];
  float s = is_hp ? (1.0f - a) : a;
  float v = vals[e] * s;
  atomicAdd(&z[(size_t)r * D + d], v * x[(size_t)c * D + d]);
}

// ---------------------------------------------------------------------------
// Kernel 3: out = relu(z @ W^T + b), out[i][j] = sum_k z[i][k] * W[j][k]
// Block: 256 threads, tile = 32 nodes x 64 j. LDS-staged z tile + W slab.
// Thread tile: 2 nodes x 4 j, float4 k-chunks.
// ---------------------------------------------------------------------------
#define NT 32
#define JT 64
#define LDP (D + 4)  // pad: row stride 132 floats (528B, 16B-aligned)

__global__ __launch_bounds__(256) void gemm_kernel(
    const float* __restrict__ z,
    const float* __restrict__ W,
    const float* __restrict__ bias,
    float* __restrict__ out,
    int n) {
  __shared__ float zt[NT][LDP];
  __shared__ float wt[JT][LDP];
  int node0 = blockIdx.x * NT;
  int j0 = blockIdx.y * JT;
  int t = threadIdx.x;

  // Stage z tile: 32*128 = 4096 floats = 1024 float4 -> 4 per thread
  #pragma unroll
  for (int it = 0; it < 4; it++) {
    int idx = t + it * 256;
    int row = idx >> 5;        // 32 float4 per row
    int c4 = idx & 31;
    int node = node0 + row;
    float4 v = make_float4(0.f, 0.f, 0.f, 0.f);
    if (node < n) v = ((const float4*)(z + (size_t)node * D))[c4];
    *(float4*)&zt[row][c4 * 4] = v;
  }
  // Stage W slab: 64*128 = 8192 floats = 2048 float4 -> 8 per thread
  #pragma unroll
  for (int it = 0; it < 8; it++) {
    int idx = t + it * 256;
    int row = idx >> 5;
    int c4 = idx & 31;
    *(float4*)&wt[row][c4 * 4] = ((const float4*)(W + (size_t)(j0 + row) * D))[c4];
  }
  __syncthreads();

  int tj = t & 15;   // 16 j-groups of 4
  int ti = t >> 4;   // 16 node-groups of 2
  int i_l = ti * 2;
  int j_l = tj * 4;

  float acc[2][4] = {};
  #pragma unroll
  for (int k = 0; k < D; k += 4) {
    float4 a0 = *(const float4*)&zt[i_l][k];
    float4 a1 = *(const float4*)&zt[i_l + 1][k];
    float4 b0 = *(const float4*)&wt[j_l][k];
    float4 b1 = *(const float4*)&wt[j_l + 1][k];
    float4 b2 = *(const float4*)&wt[j_l + 2][k];
    float4 b3 = *(const float4*)&wt[j_l + 3][k];
    acc[0][0] += a0.x * b0.x + a0.y * b0.y + a0.z * b0.z + a0.w * b0.w;
    acc[0][1] += a0.x * b1.x + a0.y * b1.y + a0.z * b1.z + a0.w * b1.w;
    acc[0][2] += a0.x * b2.x + a0.y * b2.y + a0.z * b2.z + a0.w * b2.w;
    acc[0][3] += a0.x * b3.x + a0.y * b3.y + a0.z * b3.z + a0.w * b3.w;
    acc[1][0] += a1.x * b0.x + a1.y * b0.y + a1.z * b0.z + a1.w * b0.w;
    acc[1][1] += a1.x * b1.x + a1.y * b1.y + a1.z * b1.z + a1.w * b1.w;
    acc[1][2] += a1.x * b2.x + a1.y * b2.y + a1.z * b2.z + a1.w * b2.w;
    acc[1][3] += a1.x * b3.x + a1.y * b3.y + a1.z * b3.z + a1.w * b3.w;
  }

  #pragma unroll
  for (int ii = 0; ii < 2; ii++) {
    int node = node0 + i_l + ii;
    if (node >= n) continue;
    #pragma unroll
    for (int jj = 0; jj < 4; jj++) {
      int j = j0 + j_l + jj;
      out[(size_t)node * D + j] = fmaxf(acc[ii][jj] + bias[j], 0.0f);
    }
  }
}

extern "C" void kernel_launch(void* const* d_in, const int* in_sizes, int n_in,
                              void* d_out, int out_size, void* d_ws, size_t ws_size,
                              hipStream_t stream) {
  const float* x = (const float*)d_in[0];
  const int* lp_rows = (const int*)d_in[1];
  const int* lp_cols = (const int*)d_in[2];
  const float* lp_vals = (const float*)d_in[3];
  const int* hp_rows = (const int*)d_in[4];
  const int* hp_cols = (const int*)d_in[5];
  const float* hp_vals = (const float*)d_in[6];
  const float* alpha_w = (const float*)d_in[7];
  const float* alpha_b = (const float*)d_in[8];
  const float* W = (const float*)d_in[9];
  const float* bias = (const float*)d_in[10];

  float* out = (float*)d_out;                      // [N, 128]
  float* alpha_out = out + (size_t)N_NODES_C * D;  // [N, 1] output tail

  float* z = (float*)d_ws;                         // [N, 128] mixed accumulator
  float* alpha_ws = z + (size_t)N_NODES_C * D;     // [N] alpha copy

  // z must be zeroed every call (d_ws is re-poisoned to 0xAA)
  hipMemsetAsync(z, 0, (size_t)N_NODES_C * D * sizeof(float), stream);

  // 1) alpha
  alpha_kernel<<<(N_NODES_C + 3) / 4, 256, 0, stream>>>(
      x, alpha_w, alpha_b, alpha_out, alpha_ws, N_NODES_C);

  // 2) fused mixed SpMM: LP edges scaled by alpha[row], HP by (1-alpha[row])
  edge_kernel<<<N_EDGES_C / 2, 256, 0, stream>>>(
      lp_rows, lp_cols, lp_vals, x, alpha_ws, z, N_EDGES_C, 0);
  edge_kernel<<<N_EDGES_C / 2, 256, 0, stream>>>(
      hp_rows, hp_cols, hp_vals, x, alpha_ws, z, N_EDGES_C, 1);

  // 3) out = relu(z @ W^T + b)
  dim3 ggrid((N_NODES_C + NT - 1) / NT, D / JT);
  gemm_kernel<<<ggrid, 256, 0, stream>>>(z, W, bias, out, N_NODES_C);
}

// Round 2
// 880.079 us; speedup vs baseline: 1.5819x; 1.5819x over previous
//
#include <hip/hip_runtime.h>

#define N_NODES_C 50000
#define N_EDGES_C 800000
#define D 128

// ---------------------------------------------------------------------------
// Kernel 1: alpha[i] = sigmoid(dot(x[i], alpha_w) + alpha_b)
// One 64-lane wave per node; each lane handles 2 of the 128 dims.
// ---------------------------------------------------------------------------
__global__ __launch_bounds__(256) void alpha_kernel(
    const float* __restrict__ x,
    const float* __restrict__ aw,
    const float* __restrict__ ab,
    float* __restrict__ alpha_out,
    float* __restrict__ alpha_ws,
    int n) {
  int wave = (int)((blockIdx.x * blockDim.x + threadIdx.x) >> 6);
  int lane = threadIdx.x & 63;
  if (wave >= n) return;
  const float* xr = x + (size_t)wave * D;
  float s = xr[lane] * aw[lane] + xr[lane + 64] * aw[lane + 64];
  #pragma unroll
  for (int off = 32; off > 0; off >>= 1)
    s += __shfl_down(s, off);
  if (lane == 0) {
    float a = 1.0f / (1.0f + __expf(-(s + ab[0])));
    alpha_out[wave] = a;
    alpha_ws[wave] = a;
  }
}

// ---------------------------------------------------------------------------
// Kernel 2: fused mixed SpMM scatter (unchanged this round).
// z[r] += scale(r) * vals[e] * x[cols[e]], scale = alpha[r] (LP) / 1-alpha (HP)
// ---------------------------------------------------------------------------
__global__ __launch_bounds__(256) void edge_kernel(
    const int* __restrict__ rows,
    const int* __restrict__ cols,
    const float* __restrict__ vals,
    const float* __restrict__ x,
    const float* __restrict__ alpha,
    float* __restrict__ z,
    int n_edges, int is_hp) {
  int e = (int)(blockIdx.x * 2 + (threadIdx.x >> 7));
  int d = threadIdx.x & 127;
  if (e >= n_edges) return;
  int r = rows[e];
  int c = cols[e];
  float a = alpha[r];
  float s = is_hp ? (1.0f - a) : a;
  float v = vals[e] * s;
  atomicAdd(&z[(size_t)r * D + d], v * x[(size_t)c * D + d]);
}

// ---------------------------------------------------------------------------
// Kernel 3: out = relu(z @ W^T + b) — spill-free rewrite.
// W held entirely in LDS ([j][132] pad → bank rotation). Block = 64 nodes,
// 4 passes of 16 staged z rows. Thread tile: 2 nodes x 4 j. ~40 live VGPRs.
// ---------------------------------------------------------------------------
#define GNODES 64
#define GP 16
#define LDP 132  // 128 + 4 pad: bank stride 132 % 32 != 0

__global__ __launch_bounds__(256) void gemm_kernel(
    const float* __restrict__ z,
    const float* __restrict__ W,
    const float* __restrict__ bias,
    float* __restrict__ out,
    int n) {
  __shared__ float wt[D][LDP];   // 128*132*4 = 67584 B
  __shared__ float zs[GP][LDP];  //  16*132*4 =  8448 B

  int t = threadIdx.x;
  int node0 = blockIdx.x * GNODES;

  // Stage all of W: 128 rows x 32 float4 = 4096 float4, 16 per thread.
  #pragma unroll
  for (int it = 0; it < 16; ++it) {
    int f = t + it * 256;
    int j = f >> 5;
    int k4 = f & 31;
    *(float4*)&wt[j][k4 * 4] = ((const float4*)W)[f];
  }

  int tj = t & 31;   // j-quad index: j = 4*tj .. 4*tj+3
  int ns = t >> 5;   // node-pair index: nodes 2*ns, 2*ns+1 within pass
  float4 bv = ((const float4*)bias)[tj];

  for (int p = 0; p < 4; ++p) {
    int nb = node0 + p * GP;
    __syncthreads();  // previous pass done reading zs (and pass0: wt staged)
    // Stage 16 z rows: 512 float4, 2 per thread (coalesced).
    #pragma unroll
    for (int it = 0; it < 2; ++it) {
      int f = t + it * 256;
      int r = f >> 5;
      int c4 = f & 31;
      int node = nb + r;
      float4 v = make_float4(0.f, 0.f, 0.f, 0.f);
      if (node < n) v = ((const float4*)(z + (size_t)node * D))[c4];
      *(float4*)&zs[r][c4 * 4] = v;
    }
    __syncthreads();

    float acc[2][4] = {};
    #pragma unroll 4
    for (int k = 0; k < D; k += 4) {
      float4 w0 = *(const float4*)&wt[tj * 4 + 0][k];
      float4 w1 = *(const float4*)&wt[tj * 4 + 1][k];
      float4 w2 = *(const float4*)&wt[tj * 4 + 2][k];
      float4 w3 = *(const float4*)&wt[tj * 4 + 3][k];
      float4 z0 = *(const float4*)&zs[ns * 2 + 0][k];
      float4 z1 = *(const float4*)&zs[ns * 2 + 1][k];
      acc[0][0] += z0.x * w0.x + z0.y * w0.y + z0.z * w0.z + z0.w * w0.w;
      acc[0][1] += z0.x * w1.x + z0.y * w1.y + z0.z * w1.z + z0.w * w1.w;
      acc[0][2] += z0.x * w2.x + z0.y * w2.y + z0.z * w2.z + z0.w * w2.w;
      acc[0][3] += z0.x * w3.x + z0.y * w3.y + z0.z * w3.z + z0.w * w3.w;
      acc[1][0] += z1.x * w0.x + z1.y * w0.y + z1.z * w0.z + z1.w * w0.w;
      acc[1][1] += z1.x * w1.x + z1.y * w1.y + z1.z * w1.z + z1.w * w1.w;
      acc[1][2] += z1.x * w2.x + z1.y * w2.y + z1.z * w2.z + z1.w * w2.w;
      acc[1][3] += z1.x * w3.x + z1.y * w3.y + z1.z * w3.z + z1.w * w3.w;
    }

    #pragma unroll
    for (int ii = 0; ii < 2; ++ii) {
      int node = nb + ns * 2 + ii;
      if (node < n) {
        float4 o;
        o.x = fmaxf(acc[ii][0] + bv.x, 0.0f);
        o.y = fmaxf(acc[ii][1] + bv.y, 0.0f);
        o.z = fmaxf(acc[ii][2] + bv.z, 0.0f);
        o.w = fmaxf(acc[ii][3] + bv.w, 0.0f);
        *(float4*)&out[(size_t)node * D + tj * 4] = o;
      }
    }
  }
}

extern "C" void kernel_launch(void* const* d_in, const int* in_sizes, int n_in,
                              void* d_out, int out_size, void* d_ws, size_t ws_size,
                              hipStream_t stream) {
  const float* x = (const float*)d_in[0];
  const int* lp_rows = (const int*)d_in[1];
  const int* lp_cols = (const int*)d_in[2];
  const float* lp_vals = (const float*)d_in[3];
  const int* hp_rows = (const int*)d_in[4];
  const int* hp_cols = (const int*)d_in[5];
  const float* hp_vals = (const float*)d_in[6];
  const float* alpha_w = (const float*)d_in[7];
  const float* alpha_b = (const float*)d_in[8];
  const float* W = (const float*)d_in[9];
  const float* bias = (const float*)d_in[10];

  float* out = (float*)d_out;                      // [N, 128]
  float* alpha_out = out + (size_t)N_NODES_C * D;  // [N, 1] output tail

  float* z = (float*)d_ws;                         // [N, 128] mixed accumulator
  float* alpha_ws = z + (size_t)N_NODES_C * D;     // [N] alpha copy

  hipMemsetAsync(z, 0, (size_t)N_NODES_C * D * sizeof(float), stream);

  alpha_kernel<<<(N_NODES_C + 3) / 4, 256, 0, stream>>>(
      x, alpha_w, alpha_b, alpha_out, alpha_ws, N_NODES_C);

  edge_kernel<<<N_EDGES_C / 2, 256, 0, stream>>>(
      lp_rows, lp_cols, lp_vals, x, alpha_ws, z, N_EDGES_C, 0);
  edge_kernel<<<N_EDGES_C / 2, 256, 0, stream>>>(
      hp_rows, hp_cols, hp_vals, x, alpha_ws, z, N_EDGES_C, 1);

  gemm_kernel<<<(N_NODES_C + GNODES - 1) / GNODES, 256, 0, stream>>>(
      z, W, bias, out, N_NODES_C);
}

// Round 3
// 546.774 us; speedup vs baseline: 2.5462x; 1.6096x over previous
//
#include <hip/hip_runtime.h>

#define N_NODES_C 50000
#define N_EDGES_C 800000
#define N_EDGES2_C (2 * N_EDGES_C)
#define D 128

// ---------------------------------------------------------------------------
// Kernel 1: alpha[i] = sigmoid(dot(x[i], alpha_w) + alpha_b), wave per node.
// ---------------------------------------------------------------------------
__global__ __launch_bounds__(256) void alpha_kernel(
    const float* __restrict__ x,
    const float* __restrict__ aw,
    const float* __restrict__ ab,
    float* __restrict__ alpha_out,
    float* __restrict__ alpha_ws,
    int n) {
  int wave = (int)((blockIdx.x * blockDim.x + threadIdx.x) >> 6);
  int lane = threadIdx.x & 63;
  if (wave >= n) return;
  const float* xr = x + (size_t)wave * D;
  float s = xr[lane] * aw[lane] + xr[lane + 64] * aw[lane + 64];
  #pragma unroll
  for (int off = 32; off > 0; off >>= 1)
    s += __shfl_down(s, off);
  if (lane == 0) {
    float a = 1.0f / (1.0f + __expf(-(s + ab[0])));
    alpha_out[wave] = a;
    alpha_ws[wave] = a;
  }
}

// ---------------------------------------------------------------------------
// Kernel 2: row histogram over BOTH operators (1.6M virtual edges).
// ---------------------------------------------------------------------------
__global__ __launch_bounds__(256) void hist_kernel(
    const int* __restrict__ lp_rows,
    const int* __restrict__ hp_rows,
    int* __restrict__ cnt) {
  int e = blockIdx.x * 256 + threadIdx.x;
  if (e >= N_EDGES2_C) return;
  int r = (e < N_EDGES_C) ? lp_rows[e] : hp_rows[e - N_EDGES_C];
  atomicAdd(&cnt[r], 1);
}

// ---------------------------------------------------------------------------
// Prefix scan of cnt[50000] -> start[] (exclusive), 3 phases, BLK=1024.
// ---------------------------------------------------------------------------
#define SCAN_BLK 1024

__global__ __launch_bounds__(SCAN_BLK) void scan1_kernel(
    const int* __restrict__ cnt, int* __restrict__ start,
    int* __restrict__ bsum, int n) {
  __shared__ int s[SCAN_BLK];
  int tid = threadIdx.x;
  int gid = blockIdx.x * SCAN_BLK + tid;
  int v = (gid < n) ? cnt[gid] : 0;
  s[tid] = v;
  __syncthreads();
  #pragma unroll
  for (int off = 1; off < SCAN_BLK; off <<= 1) {
    int t = (tid >= off) ? s[tid - off] : 0;
    __syncthreads();
    s[tid] += t;
    __syncthreads();
  }
  if (gid < n) start[gid] = s[tid] - v;  // exclusive within block
  if (tid == SCAN_BLK - 1) bsum[blockIdx.x] = s[tid];
}

__global__ __launch_bounds__(64) void scan2_kernel(
    int* __restrict__ bsum, int nb) {
  if (threadIdx.x == 0) {
    int run = 0;
    for (int i = 0; i < nb; ++i) {
      int v = bsum[i];
      bsum[i] = run;
      run += v;
    }
  }
}

__global__ __launch_bounds__(SCAN_BLK) void scan3_kernel(
    int* __restrict__ start, int* __restrict__ cursor,
    const int* __restrict__ bsum, int n) {
  int gid = blockIdx.x * SCAN_BLK + threadIdx.x;
  if (gid < n) {
    int v = start[gid] + bsum[blockIdx.x];
    start[gid] = v;
    cursor[gid] = v;
  }
  if (gid == n) start[n] = N_EDGES2_C;
}

// ---------------------------------------------------------------------------
// Kernel 3: fill buckets with (col, gate-scaled val); alpha folded per edge.
// ---------------------------------------------------------------------------
__global__ __launch_bounds__(256) void fill_kernel(
    const int* __restrict__ lp_rows, const int* __restrict__ lp_cols,
    const float* __restrict__ lp_vals,
    const int* __restrict__ hp_rows, const int* __restrict__ hp_cols,
    const float* __restrict__ hp_vals,
    const float* __restrict__ alpha,
    int* __restrict__ cursor,
    int* __restrict__ cols_s, float* __restrict__ vals_s) {
  int e = blockIdx.x * 256 + threadIdx.x;
  if (e >= N_EDGES2_C) return;
  int r, c;
  float v;
  if (e < N_EDGES_C) {
    r = lp_rows[e];
    c = lp_cols[e];
    v = lp_vals[e] * alpha[r];
  } else {
    int i = e - N_EDGES_C;
    r = hp_rows[i];
    c = hp_cols[i];
    v = hp_vals[i] * (1.0f - alpha[r]);
  }
  int p = atomicAdd(&cursor[r], 1);
  cols_s[p] = c;
  vals_s[p] = v;
}

// ---------------------------------------------------------------------------
// Kernel 4: gather — one wave per row, z_mix[r] = sum_p v_p * x[c_p].
// Plain stores, no atomics, z written exactly once.
// ---------------------------------------------------------------------------
__global__ __launch_bounds__(256) void gather_kernel(
    const int* __restrict__ start,
    const int* __restrict__ cols_s,
    const float* __restrict__ vals_s,
    const float* __restrict__ x,
    float* __restrict__ z) {
  int wave = (int)((blockIdx.x * blockDim.x + threadIdx.x) >> 6);
  int lane = threadIdx.x & 63;
  if (wave >= N_NODES_C) return;
  int b = start[wave];
  int e = start[wave + 1];
  float a0 = 0.f, a1 = 0.f;
  for (int p = b; p < e; ++p) {
    int c = cols_s[p];
    float v = vals_s[p];
    const float* xr = x + (size_t)c * D;
    a0 += v * xr[lane];
    a1 += v * xr[lane + 64];
  }
  z[(size_t)wave * D + lane] = a0;
  z[(size_t)wave * D + lane + 64] = a1;
}

// ---------------------------------------------------------------------------
// Kernel 5: out = relu(z @ W^T + b). W in LDS, 64 nodes/block in 4 passes.
// ---------------------------------------------------------------------------
#define GNODES 64
#define GP 16
#define LDP 132

__global__ __launch_bounds__(256) void gemm_kernel(
    const float* __restrict__ z,
    const float* __restrict__ W,
    const float* __restrict__ bias,
    float* __restrict__ out,
    int n) {
  __shared__ float wt[D][LDP];
  __shared__ float zs[GP][LDP];

  int t = threadIdx.x;
  int node0 = blockIdx.x * GNODES;

  #pragma unroll
  for (int it = 0; it < 16; ++it) {
    int f = t + it * 256;
    int j = f >> 5;
    int k4 = f & 31;
    *(float4*)&wt[j][k4 * 4] = ((const float4*)W)[f];
  }

  int tj = t & 31;
  int ns = t >> 5;
  float4 bv = ((const float4*)bias)[tj];

  for (int p = 0; p < 4; ++p) {
    int nb = node0 + p * GP;
    __syncthreads();
    #pragma unroll
    for (int it = 0; it < 2; ++it) {
      int f = t + it * 256;
      int r = f >> 5;
      int c4 = f & 31;
      int node = nb + r;
      float4 v = make_float4(0.f, 0.f, 0.f, 0.f);
      if (node < n) v = ((const float4*)(z + (size_t)node * D))[c4];
      *(float4*)&zs[r][c4 * 4] = v;
    }
    __syncthreads();

    float acc[2][4] = {};
    #pragma unroll 4
    for (int k = 0; k < D; k += 4) {
      float4 w0 = *(const float4*)&wt[tj * 4 + 0][k];
      float4 w1 = *(const float4*)&wt[tj * 4 + 1][k];
      float4 w2 = *(const float4*)&wt[tj * 4 + 2][k];
      float4 w3 = *(const float4*)&wt[tj * 4 + 3][k];
      float4 z0 = *(const float4*)&zs[ns * 2 + 0][k];
      float4 z1 = *(const float4*)&zs[ns * 2 + 1][k];
      acc[0][0] += z0.x * w0.x + z0.y * w0.y + z0.z * w0.z + z0.w * w0.w;
      acc[0][1] += z0.x * w1.x + z0.y * w1.y + z0.z * w1.z + z0.w * w1.w;
      acc[0][2] += z0.x * w2.x + z0.y * w2.y + z0.z * w2.z + z0.w * w2.w;
      acc[0][3] += z0.x * w3.x + z0.y * w3.y + z0.z * w3.z + z0.w * w3.w;
      acc[1][0] += z1.x * w0.x + z1.y * w0.y + z1.z * w0.z + z1.w * w0.w;
      acc[1][1] += z1.x * w1.x + z1.y * w1.y + z1.z * w1.z + z1.w * w1.w;
      acc[1][2] += z1.x * w2.x + z1.y * w2.y + z1.z * w2.z + z1.w * w2.w;
      acc[1][3] += z1.x * w3.x + z1.y * w3.y + z1.z * w3.z + z1.w * w3.w;
    }

    #pragma unroll
    for (int ii = 0; ii < 2; ++ii) {
      int node = nb + ns * 2 + ii;
      if (node < n) {
        float4 o;
        o.x = fmaxf(acc[ii][0] + bv.x, 0.0f);
        o.y = fmaxf(acc[ii][1] + bv.y, 0.0f);
        o.z = fmaxf(acc[ii][2] + bv.z, 0.0f);
        o.w = fmaxf(acc[ii][3] + bv.w, 0.0f);
        *(float4*)&out[(size_t)node * D + tj * 4] = o;
      }
    }
  }
}

extern "C" void kernel_launch(void* const* d_in, const int* in_sizes, int n_in,
                              void* d_out, int out_size, void* d_ws, size_t ws_size,
                              hipStream_t stream) {
  const float* x = (const float*)d_in[0];
  const int* lp_rows = (const int*)d_in[1];
  const int* lp_cols = (const int*)d_in[2];
  const float* lp_vals = (const float*)d_in[3];
  const int* hp_rows = (const int*)d_in[4];
  const int* hp_cols = (const int*)d_in[5];
  const float* hp_vals = (const float*)d_in[6];
  const float* alpha_w = (const float*)d_in[7];
  const float* alpha_b = (const float*)d_in[8];
  const float* W = (const float*)d_in[9];
  const float* bias = (const float*)d_in[10];

  float* out = (float*)d_out;                      // [N, 128]
  float* alpha_out = out + (size_t)N_NODES_C * D;  // [N, 1] output tail

  // Workspace carve-up (all 256B-aligned):
  char* ws = (char*)d_ws;
  float* z = (float*)ws;                 ws += (size_t)N_NODES_C * D * 4;   // 25.6 MB
  float* alpha_ws = (float*)ws;          ws += 200192;                      // 50000 f
  int* cnt = (int*)ws;                   ws += 200192;                      // 50000 i
  int* start = (int*)ws;                 ws += 200448;                      // 50001 i
  int* cursor = (int*)ws;                ws += 200192;                      // 50000 i
  int* bsum = (int*)ws;                  ws += 256;                         // 49 i
  int* cols_s = (int*)ws;                ws += (size_t)N_EDGES2_C * 4;      // 6.4 MB
  float* vals_s = (float*)ws;            ws += (size_t)N_EDGES2_C * 4;      // 6.4 MB

  hipMemsetAsync(cnt, 0, N_NODES_C * sizeof(int), stream);

  alpha_kernel<<<(N_NODES_C + 3) / 4, 256, 0, stream>>>(
      x, alpha_w, alpha_b, alpha_out, alpha_ws, N_NODES_C);

  hist_kernel<<<(N_EDGES2_C + 255) / 256, 256, 0, stream>>>(
      lp_rows, hp_rows, cnt);

  int nsb = (N_NODES_C + SCAN_BLK - 1) / SCAN_BLK;  // 49
  scan1_kernel<<<nsb, SCAN_BLK, 0, stream>>>(cnt, start, bsum, N_NODES_C);
  scan2_kernel<<<1, 64, 0, stream>>>(bsum, nsb);
  scan3_kernel<<<nsb, SCAN_BLK, 0, stream>>>(start, cursor, bsum, N_NODES_C);

  fill_kernel<<<(N_EDGES2_C + 255) / 256, 256, 0, stream>>>(
      lp_rows, lp_cols, lp_vals, hp_rows, hp_cols, hp_vals,
      alpha_ws, cursor, cols_s, vals_s);

  gather_kernel<<<(N_NODES_C * 64 + 255) / 256, 256, 0, stream>>>(
      start, cols_s, vals_s, x, z);

  gemm_kernel<<<(N_NODES_C + GNODES - 1) / GNODES, 256, 0, stream>>>(
      z, W, bias, out, N_NODES_C);
}

// Round 4
// 418.045 us; speedup vs baseline: 3.3302x; 1.3079x over previous
//
#include <hip/hip_runtime.h>

#define N_NODES_C 50000
#define N_EDGES_C 800000
#define N_EDGES2_C (2 * N_EDGES_C)
#define D 128

static __device__ __forceinline__ unsigned short f2bf(float f) {
  unsigned u = __float_as_uint(f);
  u += 0x7fff + ((u >> 16) & 1);  // round-to-nearest-even
  return (unsigned short)(u >> 16);
}
static __device__ __forceinline__ float bf_lo(unsigned u) {  // low 16 bits
  return __uint_as_float(u << 16);
}
static __device__ __forceinline__ float bf_hi(unsigned u) {  // high 16 bits
  return __uint_as_float(u & 0xffff0000u);
}

// ---------------------------------------------------------------------------
// Kernel 1: alpha[i] = sigmoid(dot(x[i], alpha_w) + alpha_b), wave per node.
// ---------------------------------------------------------------------------
__global__ __launch_bounds__(256) void alpha_kernel(
    const float* __restrict__ x,
    const float* __restrict__ aw,
    const float* __restrict__ ab,
    float* __restrict__ alpha_out,
    float* __restrict__ alpha_ws,
    int n) {
  int wave = (int)((blockIdx.x * blockDim.x + threadIdx.x) >> 6);
  int lane = threadIdx.x & 63;
  if (wave >= n) return;
  const float* xr = x + (size_t)wave * D;
  float s = xr[lane] * aw[lane] + xr[lane + 64] * aw[lane + 64];
  #pragma unroll
  for (int off = 32; off > 0; off >>= 1)
    s += __shfl_down(s, off);
  if (lane == 0) {
    float a = 1.0f / (1.0f + __expf(-(s + ab[0])));
    alpha_out[wave] = a;
    alpha_ws[wave] = a;
  }
}

// ---------------------------------------------------------------------------
// Kernel 2: row histogram over BOTH operators (1.6M virtual edges).
// ---------------------------------------------------------------------------
__global__ __launch_bounds__(256) void hist_kernel(
    const int* __restrict__ lp_rows,
    const int* __restrict__ hp_rows,
    int* __restrict__ cnt) {
  int e = blockIdx.x * 256 + threadIdx.x;
  if (e >= N_EDGES2_C) return;
  int r = (e < N_EDGES_C) ? lp_rows[e] : hp_rows[e - N_EDGES_C];
  atomicAdd(&cnt[r], 1);
}

// ---------------------------------------------------------------------------
// Prefix scan of cnt[50000] -> start[] (exclusive), 3 phases, BLK=1024.
// ---------------------------------------------------------------------------
#define SCAN_BLK 1024

__global__ __launch_bounds__(SCAN_BLK) void scan1_kernel(
    const int* __restrict__ cnt, int* __restrict__ start,
    int* __restrict__ bsum, int n) {
  __shared__ int s[SCAN_BLK];
  int tid = threadIdx.x;
  int gid = blockIdx.x * SCAN_BLK + tid;
  int v = (gid < n) ? cnt[gid] : 0;
  s[tid] = v;
  __syncthreads();
  #pragma unroll
  for (int off = 1; off < SCAN_BLK; off <<= 1) {
    int t = (tid >= off) ? s[tid - off] : 0;
    __syncthreads();
    s[tid] += t;
    __syncthreads();
  }
  if (gid < n) start[gid] = s[tid] - v;
  if (tid == SCAN_BLK - 1) bsum[blockIdx.x] = s[tid];
}

__global__ __launch_bounds__(64) void scan2_kernel(
    int* __restrict__ bsum, int nb) {
  if (threadIdx.x == 0) {
    int run = 0;
    for (int i = 0; i < nb; ++i) {
      int v = bsum[i];
      bsum[i] = run;
      run += v;
    }
  }
}

__global__ __launch_bounds__(SCAN_BLK) void scan3_kernel(
    int* __restrict__ start, int* __restrict__ cursor,
    const int* __restrict__ bsum, int n) {
  int gid = blockIdx.x * SCAN_BLK + threadIdx.x;
  if (gid < n) {
    int v = start[gid] + bsum[blockIdx.x];
    start[gid] = v;
    cursor[gid] = v;
  }
  if (gid == n) start[n] = N_EDGES2_C;
}

// ---------------------------------------------------------------------------
// Kernel 3: fill buckets with packed (col, gate-scaled val) int2.
// ---------------------------------------------------------------------------
__global__ __launch_bounds__(256) void fill_kernel(
    const int* __restrict__ lp_rows, const int* __restrict__ lp_cols,
    const float* __restrict__ lp_vals,
    const int* __restrict__ hp_rows, const int* __restrict__ hp_cols,
    const float* __restrict__ hp_vals,
    const float* __restrict__ alpha,
    int* __restrict__ cursor,
    int2* __restrict__ pairs) {
  int e = blockIdx.x * 256 + threadIdx.x;
  if (e >= N_EDGES2_C) return;
  int r, c;
  float v;
  if (e < N_EDGES_C) {
    r = lp_rows[e];
    c = lp_cols[e];
    v = lp_vals[e] * alpha[r];
  } else {
    int i = e - N_EDGES_C;
    r = hp_rows[i];
    c = hp_cols[i];
    v = hp_vals[i] * (1.0f - alpha[r]);
  }
  int p = atomicAdd(&cursor[r], 1);
  pairs[p] = make_int2(c, __float_as_int(v));
}

// ---------------------------------------------------------------------------
// Kernel 4: gemm_y: y = x @ W^T, stored bf16. W in LDS, 64 nodes/block.
// ---------------------------------------------------------------------------
#define GNODES 64
#define GP 16
#define LDP 132

__global__ __launch_bounds__(256) void gemm_y_kernel(
    const float* __restrict__ x,
    const float* __restrict__ W,
    unsigned short* __restrict__ y,
    int n) {
  __shared__ float wt[D][LDP];
  __shared__ float zs[GP][LDP];

  int t = threadIdx.x;
  int node0 = blockIdx.x * GNODES;

  #pragma unroll
  for (int it = 0; it < 16; ++it) {
    int f = t + it * 256;
    int j = f >> 5;
    int k4 = f & 31;
    *(float4*)&wt[j][k4 * 4] = ((const float4*)W)[f];
  }

  int tj = t & 31;
  int ns = t >> 5;

  for (int p = 0; p < 4; ++p) {
    int nb = node0 + p * GP;
    __syncthreads();
    #pragma unroll
    for (int it = 0; it < 2; ++it) {
      int f = t + it * 256;
      int r = f >> 5;
      int c4 = f & 31;
      int node = nb + r;
      float4 v = make_float4(0.f, 0.f, 0.f, 0.f);
      if (node < n) v = ((const float4*)(x + (size_t)node * D))[c4];
      *(float4*)&zs[r][c4 * 4] = v;
    }
    __syncthreads();

    float acc[2][4] = {};
    #pragma unroll 4
    for (int k = 0; k < D; k += 4) {
      float4 w0 = *(const float4*)&wt[tj * 4 + 0][k];
      float4 w1 = *(const float4*)&wt[tj * 4 + 1][k];
      float4 w2 = *(const float4*)&wt[tj * 4 + 2][k];
      float4 w3 = *(const float4*)&wt[tj * 4 + 3][k];
      float4 z0 = *(const float4*)&zs[ns * 2 + 0][k];
      float4 z1 = *(const float4*)&zs[ns * 2 + 1][k];
      acc[0][0] += z0.x * w0.x + z0.y * w0.y + z0.z * w0.z + z0.w * w0.w;
      acc[0][1] += z0.x * w1.x + z0.y * w1.y + z0.z * w1.z + z0.w * w1.w;
      acc[0][2] += z0.x * w2.x + z0.y * w2.y + z0.z * w2.z + z0.w * w2.w;
      acc[0][3] += z0.x * w3.x + z0.y * w3.y + z0.z * w3.z + z0.w * w3.w;
      acc[1][0] += z1.x * w0.x + z1.y * w0.y + z1.z * w0.z + z1.w * w0.w;
      acc[1][1] += z1.x * w1.x + z1.y * w1.y + z1.z * w1.z + z1.w * w1.w;
      acc[1][2] += z1.x * w2.x + z1.y * w2.y + z1.z * w2.z + z1.w * w2.w;
      acc[1][3] += z1.x * w3.x + z1.y * w3.y + z1.z * w3.z + z1.w * w3.w;
    }

    #pragma unroll
    for (int ii = 0; ii < 2; ++ii) {
      int node = nb + ns * 2 + ii;
      if (node < n) {
        ushort4 o;
        o.x = f2bf(acc[ii][0]);
        o.y = f2bf(acc[ii][1]);
        o.z = f2bf(acc[ii][2]);
        o.w = f2bf(acc[ii][3]);
        *(ushort4*)&y[(size_t)node * D + tj * 4] = o;
      }
    }
  }
}

// ---------------------------------------------------------------------------
// Kernel 5: gather over bf16 y + fused bias/ReLU epilogue.
// Wave per row; lane owns dims {2*lane, 2*lane+1} (one uint = bf16x2).
// out[r] = relu( sum_p v_p * y[c_p] + b ), written once, no atomics.
// ---------------------------------------------------------------------------
__global__ __launch_bounds__(256) void gather_kernel(
    const int* __restrict__ start,
    const int2* __restrict__ pairs,
    const unsigned* __restrict__ y,   // [N][64] uints (bf16x2)
    const float* __restrict__ bias,
    float* __restrict__ out) {
  int row = (int)((blockIdx.x * blockDim.x + threadIdx.x) >> 6);
  int lane = threadIdx.x & 63;
  if (row >= N_NODES_C) return;
  int b = start[row];
  int e = start[row + 1];
  float aL = 0.f, aH = 0.f;
  int p = b;
  for (; p + 3 < e; p += 4) {
    int2 e0 = pairs[p + 0];
    int2 e1 = pairs[p + 1];
    int2 e2 = pairs[p + 2];
    int2 e3 = pairs[p + 3];
    unsigned u0 = y[(size_t)e0.x * 64 + lane];
    unsigned u1 = y[(size_t)e1.x * 64 + lane];
    unsigned u2 = y[(size_t)e2.x * 64 + lane];
    unsigned u3 = y[(size_t)e3.x * 64 + lane];
    float v0 = __int_as_float(e0.y);
    float v1 = __int_as_float(e1.y);
    float v2 = __int_as_float(e2.y);
    float v3 = __int_as_float(e3.y);
    aL += v0 * bf_lo(u0) + v1 * bf_lo(u1) + v2 * bf_lo(u2) + v3 * bf_lo(u3);
    aH += v0 * bf_hi(u0) + v1 * bf_hi(u1) + v2 * bf_hi(u2) + v3 * bf_hi(u3);
  }
  for (; p < e; ++p) {
    int2 e0 = pairs[p];
    unsigned u0 = y[(size_t)e0.x * 64 + lane];
    float v0 = __int_as_float(e0.y);
    aL += v0 * bf_lo(u0);
    aH += v0 * bf_hi(u0);
  }
  float2 bv = *(const float2*)&bias[lane * 2];
  float2 o;
  o.x = fmaxf(aL + bv.x, 0.0f);
  o.y = fmaxf(aH + bv.y, 0.0f);
  *(float2*)&out[(size_t)row * D + lane * 2] = o;
}

extern "C" void kernel_launch(void* const* d_in, const int* in_sizes, int n_in,
                              void* d_out, int out_size, void* d_ws, size_t ws_size,
                              hipStream_t stream) {
  const float* x = (const float*)d_in[0];
  const int* lp_rows = (const int*)d_in[1];
  const int* lp_cols = (const int*)d_in[2];
  const float* lp_vals = (const float*)d_in[3];
  const int* hp_rows = (const int*)d_in[4];
  const int* hp_cols = (const int*)d_in[5];
  const float* hp_vals = (const float*)d_in[6];
  const float* alpha_w = (const float*)d_in[7];
  const float* alpha_b = (const float*)d_in[8];
  const float* W = (const float*)d_in[9];
  const float* bias = (const float*)d_in[10];

  float* out = (float*)d_out;                      // [N, 128]
  float* alpha_out = out + (size_t)N_NODES_C * D;  // [N, 1] output tail

  // Workspace carve-up (all 256B-aligned):
  char* ws = (char*)d_ws;
  unsigned short* y = (unsigned short*)ws;
  ws += (size_t)N_NODES_C * D * 2;                 // 12.8 MB bf16 y
  float* alpha_ws = (float*)ws;          ws += 200192;
  int* cnt = (int*)ws;                   ws += 200192;
  int* start = (int*)ws;                 ws += 200448;
  int* cursor = (int*)ws;                ws += 200192;
  int* bsum = (int*)ws;                  ws += 256;
  int2* pairs = (int2*)ws;               ws += (size_t)N_EDGES2_C * 8;  // 12.8 MB

  hipMemsetAsync(cnt, 0, N_NODES_C * sizeof(int), stream);

  alpha_kernel<<<(N_NODES_C + 3) / 4, 256, 0, stream>>>(
      x, alpha_w, alpha_b, alpha_out, alpha_ws, N_NODES_C);

  hist_kernel<<<(N_EDGES2_C + 255) / 256, 256, 0, stream>>>(
      lp_rows, hp_rows, cnt);

  int nsb = (N_NODES_C + SCAN_BLK - 1) / SCAN_BLK;  // 49
  scan1_kernel<<<nsb, SCAN_BLK, 0, stream>>>(cnt, start, bsum, N_NODES_C);
  scan2_kernel<<<1, 64, 0, stream>>>(bsum, nsb);
  scan3_kernel<<<nsb, SCAN_BLK, 0, stream>>>(start, cursor, bsum, N_NODES_C);

  fill_kernel<<<(N_EDGES2_C + 255) / 256, 256, 0, stream>>>(
      lp_rows, lp_cols, lp_vals, hp_rows, hp_cols, hp_vals,
      alpha_ws, cursor, pairs);

  gemm_y_kernel<<<(N_NODES_C + GNODES - 1) / GNODES, 256, 0, stream>>>(
      x, W, y, N_NODES_C);

  gather_kernel<<<(N_NODES_C * 64 + 255) / 256, 256, 0, stream>>>(
      start, pairs, (const unsigned*)y, bias, out);
}